// Round 1
// 2136.973 us; speedup vs baseline: 1.1761x; 1.1761x over previous
//
#include <hip/hip_runtime.h>
#include <math.h>

#define DIM   64
#define KNB   32
#define ROWS  33                 // self + 32 neighbors
#define VFLOAT (ROWS * DIM)      // 2112 floats per node buffer
#define WAVES_PER_BLOCK 2
#define BLOCK_THREADS (WAVES_PER_BLOCK * 64)
#define GRID_BLOCKS 2048

typedef const __attribute__((address_space(1))) void* gva_t;
typedef __attribute__((address_space(3))) void* lva_t;

__device__ __forceinline__ void load16_lds(const float* g, float* l) {
  // async global->LDS, 16B per active lane at (uniform base + lane*16)
  __builtin_amdgcn_global_load_lds((gva_t)g, (lva_t)l, 16, 0, 0);
}
__device__ __forceinline__ void wait_vm0() {
  asm volatile("s_waitcnt vmcnt(0)" ::: "memory");
}
__device__ __forceinline__ void lds_fence() {
  asm volatile("s_waitcnt lgkmcnt(0)" ::: "memory");
}
// order-preserving float <-> uint mapping for atomicMax on floats
__device__ __forceinline__ unsigned enc_f(float f) {
  unsigned u = __float_as_uint(f);
  return (u & 0x80000000u) ? ~u : (u | 0x80000000u);
}
__device__ __forceinline__ float dec_f(unsigned e) {
  unsigned u = (e & 0x80000000u) ? (e & 0x7fffffffu) : ~e;
  return __uint_as_float(u);
}

__global__ __launch_bounds__(BLOCK_THREADS, 2) void
sage_stage1(const float* __restrict__ x_self,
            const float* __restrict__ x_nb,
            const float* __restrict__ a1W,
            const float* __restrict__ a1b,
            const float* __restrict__ e1W,
            const float* __restrict__ a2W,
            unsigned* __restrict__ zenc,
            int N)
{
  // per-wave: double-buffered node data + one exchange row
  __shared__ __align__(16) float smem[WAVES_PER_BLOCK * (2 * VFLOAT + DIM)];
  const int lane = threadIdx.x & 63;
  const int wv   = threadIdx.x >> 6;
  float* const wbase = &smem[wv * (2 * VFLOAT + DIM)];
  float* const V0  = wbase;
  float* const V1  = wbase + VFLOAT;
  float* const xch = wbase + 2 * VFLOAT;

  // ONLY the hot weight matrix (read 33x per node) lives in registers.
  // e1W / a2W rows are streamed from L1/L2 once per node instead — keeping
  // all three (192 floats/lane) forced the allocator to spill to scratch,
  // which was the dominant cost (154 MB scratch stores + L3-latency reloads).
  float w1[DIM];
  {
    const float4* p1 = (const float4*)(a1W + lane * DIM);
#pragma unroll
    for (int t = 0; t < 16; ++t) {
      float4 a = p1[t];
      w1[4*t+0] = a.x; w1[4*t+1] = a.y; w1[4*t+2] = a.z; w1[4*t+3] = a.w;
    }
  }
  const float b1 = a1b[lane];

  const int wid    = blockIdx.x * WAVES_PER_BLOCK + wv;
  const int stride = gridDim.x * WAVES_PER_BLOCK;

  float zmax = -INFINITY;

  auto issue_load = [&](int n, float* dst) {
    if (lane < 16)
      load16_lds(x_self + (size_t)n * DIM + lane * 4, dst);
    const float* src = x_nb + (size_t)n * (KNB * DIM) + lane * 4;
#pragma unroll
    for (int i = 0; i < 8; ++i)
      load16_lds(src + i * 256, dst + DIM + i * 256);
  };

  int n = wid;
  int cur = 0;
  if (n < N) issue_load(n, V0);

  while (n < N) {
    wait_vm0();                       // current buffer resident in LDS
    const int nn = n + stride;
    float* const Vc = cur ? V1 : V0;
    float* const Vn = cur ? V0 : V1;
    if (nn < N) issue_load(nn, Vn);   // prefetch overlaps compute below

    // ---- stage-1 pooling: m[o] = max_j dot(V[j,:], aggr1_W[o,:]) ----
    float m = -INFINITY;
    for (int j = 0; j < ROWS; ++j) {
      const float4* vp = (const float4*)(Vc + j * DIM);  // broadcast reads
      float a0 = 0.f, a1v = 0.f, a2v = 0.f, a3 = 0.f;
#pragma unroll
      for (int t = 0; t < 16; ++t) {
        float4 v = vp[t];
        a0  = fmaf(v.x, w1[4*t+0], a0);
        a1v = fmaf(v.y, w1[4*t+1], a1v);
        a2v = fmaf(v.z, w1[4*t+2], a2v);
        a3  = fmaf(v.w, w1[4*t+3], a3);
      }
      m = fmaxf(m, (a0 + a1v) + (a2v + a3));
    }
    const float aggr = fmaxf(m + b1, 0.0f);   // relu(max + b) == max(relu(..+b))

    // ---- emb1 matvec + relu (weight row streamed from L1/L2) ----
    lds_fence();               // prior reads of xch complete before overwrite
    xch[lane] = aggr;
    lds_fence();               // writes visible before reads (lockstep wave)
    float e0 = 0.f, e1 = 0.f, e2 = 0.f, e3 = 0.f;
    {
      const float4* ap = (const float4*)xch;
      const float4* wp = (const float4*)(e1W + lane * DIM);
      asm volatile("" : "+v"(wp));   // opaque ptr: forbid LICM re-hoisting loads
#pragma unroll 1
      for (int h = 0; h < 2; ++h) {  // 2 batches of 8 float4 caps reg pressure
#pragma unroll
        for (int t = 0; t < 8; ++t) {
          float4 w = wp[h * 8 + t];
          float4 v = ap[h * 8 + t];
          e0 = fmaf(v.x, w.x, e0);
          e1 = fmaf(v.y, w.y, e1);
          e2 = fmaf(v.z, w.z, e2);
          e3 = fmaf(v.w, w.w, e3);
        }
      }
    }
    float e = fmaxf((e0 + e1) + (e2 + e3), 0.0f);

    // ---- l2 normalize across wave (64 dims = 64 lanes) ----
    float ss = e * e;
#pragma unroll
    for (int off = 32; off > 0; off >>= 1)
      ss += __shfl_xor(ss, off, 64);
    float den = sqrtf(ss);
    den = (den > 0.0f) ? den : 1.0f;
    const float en = e / den;

    // ---- stage-2 partial: z[o] = en . aggr2_W[o,:], running max ----
    lds_fence();
    xch[lane] = en;
    lds_fence();
    float z0 = 0.f, z1 = 0.f, z2 = 0.f, z3 = 0.f;
    {
      const float4* ep = (const float4*)xch;
      const float4* wp = (const float4*)(a2W + lane * DIM);
      asm volatile("" : "+v"(wp));   // opaque ptr: forbid LICM re-hoisting loads
#pragma unroll 1
      for (int h = 0; h < 2; ++h) {
#pragma unroll
        for (int t = 0; t < 8; ++t) {
          float4 w = wp[h * 8 + t];
          float4 v = ep[h * 8 + t];
          z0 = fmaf(v.x, w.x, z0);
          z1 = fmaf(v.y, w.y, z1);
          z2 = fmaf(v.z, w.z, z2);
          z3 = fmaf(v.w, w.w, z3);
        }
      }
    }
    zmax = fmaxf(zmax, (z0 + z1) + (z2 + z3));

    n = nn;
    cur ^= 1;
  }

  // device-scope atomic max per output dim (ws was memset to 0 < enc(any real))
  atomicMax(&zenc[lane], enc_f(zmax));
}

__global__ void sage_stage2(const unsigned* __restrict__ zenc,
                            const float* __restrict__ a2b,
                            const float* __restrict__ e2W,
                            const float* __restrict__ rW1,
                            const float* __restrict__ rb1,
                            const float* __restrict__ rW2,
                            const float* __restrict__ rb2,
                            float* __restrict__ out)
{
  const int o = threadIdx.x;   // 64 threads, one wave
  __shared__ float sh[DIM];
  float a2 = fmaxf(dec_f(zenc[o]) + a2b[o], 0.0f);
  sh[o] = a2;
  __syncthreads();
  float e = 0.f;
#pragma unroll
  for (int d = 0; d < DIM; ++d) e = fmaf(sh[d], e2W[o * DIM + d], e);
  e = fmaxf(e, 0.0f);
  float ss = e * e;
#pragma unroll
  for (int off = 32; off > 0; off >>= 1) ss += __shfl_xor(ss, off, 64);
  float den = sqrtf(ss);
  den = (den > 0.0f) ? den : 1.0f;
  const float en = e / den;
  __syncthreads();
  sh[o] = en;
  __syncthreads();
  float h = rb1[o];
#pragma unroll
  for (int d = 0; d < DIM; ++d) h = fmaf(sh[d], rW1[o * DIM + d], h);
  h = fmaxf(h, 0.0f);
  float p = h * rW2[o];
#pragma unroll
  for (int off = 32; off > 0; off >>= 1) p += __shfl_xor(p, off, 64);
  if (o == 0) out[0] = p + rb2[0];
}

extern "C" void kernel_launch(void* const* d_in, const int* in_sizes, int n_in,
                              void* d_out, int out_size, void* d_ws, size_t ws_size,
                              hipStream_t stream) {
  (void)n_in; (void)out_size; (void)ws_size;
  const float* x_self = (const float*)d_in[0];
  const float* x_nb   = (const float*)d_in[1];
  const float* a1W    = (const float*)d_in[2];
  const float* a1b    = (const float*)d_in[3];
  const float* e1W    = (const float*)d_in[4];
  const float* a2W    = (const float*)d_in[5];
  const float* a2b    = (const float*)d_in[6];
  const float* e2W    = (const float*)d_in[7];
  const float* rW1    = (const float*)d_in[8];
  const float* rb1    = (const float*)d_in[9];
  const float* rW2    = (const float*)d_in[10];
  const float* rb2    = (const float*)d_in[11];

  const int N = in_sizes[0] / DIM;
  unsigned* zenc = (unsigned*)d_ws;

  // 0 encodes below every real float's ordered encoding -> safe max identity
  hipMemsetAsync(zenc, 0, DIM * sizeof(unsigned), stream);
  sage_stage1<<<GRID_BLOCKS, BLOCK_THREADS, 0, stream>>>(
      x_self, x_nb, a1W, a1b, e1W, a2W, zenc, N);
  sage_stage2<<<1, 64, 0, stream>>>(zenc, a2b, e2W, rW1, rb1, rW2, rb2,
                                    (float*)d_out);
}